// Round 1
// baseline (65630.243 us; speedup 1.0000x reference)
//
#include <hip/hip_runtime.h>
#include <hip/hip_bf16.h>

#define B   256
#define S   192
#define F   64
#define HD  1024
#define L   2
#define PRED 48

// ---------------------------------------------------------------------------
// fold_kernel: Wfold[f][n] = sum_hd W_hidden[f][hd] * Wih0[hd][n]
// grid: 64 blocks x 256 thr ; block = (ntile 0..3, fgroup 0..15), 4 f per block
// ---------------------------------------------------------------------------
__global__ void fold_kernel(const float* __restrict__ Wh,
                            const float* __restrict__ Wih0,
                            float* __restrict__ Wfold) {
    const int n  = (blockIdx.x & 3) * 256 + threadIdx.x;
    const int f0 = (blockIdx.x >> 2) * 4;
    float a0 = 0.f, a1 = 0.f, a2 = 0.f, a3 = 0.f;
#pragma unroll 8
    for (int k = 0; k < HD; ++k) {
        const float w = Wih0[(size_t)k * HD + n];
        a0 += Wh[(f0 + 0) * HD + k] * w;
        a1 += Wh[(f0 + 1) * HD + k] * w;
        a2 += Wh[(f0 + 2) * HD + k] * w;
        a3 += Wh[(f0 + 3) * HD + k] * w;
    }
    Wfold[(f0 + 0) * HD + n] = a0;
    Wfold[(f0 + 1) * HD + n] = a1;
    Wfold[(f0 + 2) * HD + n] = a2;
    Wfold[(f0 + 3) * HD + n] = a3;
}

// ---------------------------------------------------------------------------
// bias_kernel: bf0[n] = b_hidden @ Wih0[:,n] + bih0[n] + bhh0[n]
//              bf1[n] = bih1[n] + bhh1[n]
// grid: 4 blocks x 256 thr
// ---------------------------------------------------------------------------
__global__ void bias_kernel(const float* __restrict__ bh,
                            const float* __restrict__ Wih0,
                            const float* __restrict__ bih,
                            const float* __restrict__ bhh,
                            float* __restrict__ bf0,
                            float* __restrict__ bf1) {
    const int n = blockIdx.x * 256 + threadIdx.x;
    float a = 0.f;
#pragma unroll 8
    for (int k = 0; k < HD; ++k) a += bh[k] * Wih0[(size_t)k * HD + n];
    bf0[n] = a + bih[n] + bhh[n];
    bf1[n] = bih[HD + n] + bhh[HD + n];
}

// ---------------------------------------------------------------------------
// layer0_step: h0_new[b][n] = tanh( x[b,t,:]@Wfold[:,n] + bf0[n]
//                                   + h0_prev[b,:]@Whh0[:,n] )
// grid: 512 blocks (32 coltiles x 16 rowtiles) x 256 thr
// tile: M=16 rows (b), N=32 cols (n); thread = (n-lane 0..31, trow 0..7),
// 2 rows/thread.
// ---------------------------------------------------------------------------
__global__ void layer0_step(const float* __restrict__ x, int t,
                            const float* __restrict__ Wfold,
                            const float* __restrict__ bf0,
                            const float* __restrict__ Whh0,
                            const float* __restrict__ hp,
                            float* __restrict__ ho) {
    const int ct = blockIdx.x & 31;
    const int rt = blockIdx.x >> 5;
    const int n  = ct * 32 + (threadIdx.x & 31);
    const int tr = threadIdx.x >> 5;      // 0..7
    const int b0 = rt * 16;

    __shared__ float xs[16][64];
    __shared__ float hs[16][64];

    // stage x rows for this block (16 x 64)
    for (int i = threadIdx.x; i < 16 * 64; i += 256) {
        const int r = i >> 6, k = i & 63;
        xs[r][k] = x[((size_t)(b0 + r) * S + t) * F + k];
    }
    __syncthreads();

    float acc0 = 0.f, acc1 = 0.f;
#pragma unroll 8
    for (int k = 0; k < F; ++k) {
        const float w = Wfold[k * HD + n];
        acc0 += xs[tr * 2 + 0][k] * w;
        acc1 += xs[tr * 2 + 1][k] * w;
    }

    for (int k0 = 0; k0 < HD; k0 += 64) {
        __syncthreads();
        for (int i = threadIdx.x; i < 16 * 64; i += 256) {
            const int r = i >> 6, k = i & 63;
            hs[r][k] = hp[(size_t)(b0 + r) * HD + k0 + k];
        }
        __syncthreads();
#pragma unroll 8
        for (int kk = 0; kk < 64; ++kk) {
            const float w = Whh0[(size_t)(k0 + kk) * HD + n];
            acc0 += hs[tr * 2 + 0][kk] * w;
            acc1 += hs[tr * 2 + 1][kk] * w;
        }
    }
    const float bb = bf0[n];
    ho[(size_t)(b0 + tr * 2 + 0) * HD + n] = tanhf(acc0 + bb);
    ho[(size_t)(b0 + tr * 2 + 1) * HD + n] = tanhf(acc1 + bb);
}

// ---------------------------------------------------------------------------
// layer1_step: h1_new[b][n] = tanh( h0_new[b,:]@Wih1[:,n]
//                                   + h1_prev[b,:]@Whh1[:,n] + bf1[n] )
// same tiling as layer0_step.
// ---------------------------------------------------------------------------
__global__ void layer1_step(const float* __restrict__ Wih1,
                            const float* __restrict__ Whh1,
                            const float* __restrict__ bf1,
                            const float* __restrict__ h0n,
                            const float* __restrict__ h1p,
                            float* __restrict__ h1o) {
    const int ct = blockIdx.x & 31;
    const int rt = blockIdx.x >> 5;
    const int n  = ct * 32 + (threadIdx.x & 31);
    const int tr = threadIdx.x >> 5;
    const int b0 = rt * 16;

    __shared__ float hs[16][64];

    float acc0 = 0.f, acc1 = 0.f;

    for (int k0 = 0; k0 < HD; k0 += 64) {
        __syncthreads();
        for (int i = threadIdx.x; i < 16 * 64; i += 256) {
            const int r = i >> 6, k = i & 63;
            hs[r][k] = h0n[(size_t)(b0 + r) * HD + k0 + k];
        }
        __syncthreads();
#pragma unroll 8
        for (int kk = 0; kk < 64; ++kk) {
            const float w = Wih1[(size_t)(k0 + kk) * HD + n];
            acc0 += hs[tr * 2 + 0][kk] * w;
            acc1 += hs[tr * 2 + 1][kk] * w;
        }
    }
    for (int k0 = 0; k0 < HD; k0 += 64) {
        __syncthreads();
        for (int i = threadIdx.x; i < 16 * 64; i += 256) {
            const int r = i >> 6, k = i & 63;
            hs[r][k] = h1p[(size_t)(b0 + r) * HD + k0 + k];
        }
        __syncthreads();
#pragma unroll 8
        for (int kk = 0; kk < 64; ++kk) {
            const float w = Whh1[(size_t)(k0 + kk) * HD + n];
            acc0 += hs[tr * 2 + 0][kk] * w;
            acc1 += hs[tr * 2 + 1][kk] * w;
        }
    }
    const float bb = bf1[n];
    h1o[(size_t)(b0 + tr * 2 + 0) * HD + n] = tanhf(acc0 + bb);
    h1o[(size_t)(b0 + tr * 2 + 1) * HD + n] = tanhf(acc1 + bb);
}

// ---------------------------------------------------------------------------
// out_step: out[b][p][f] = relu(h1[b,:]) @ Wo[:,f] + bo[f]
// grid: 64 blocks x 256 thr ; block handles 4 rows b, thread = (f 0..63, row 0..3)
// ---------------------------------------------------------------------------
__global__ void out_step(const float* __restrict__ h1,
                         const float* __restrict__ Wo,
                         const float* __restrict__ bo,
                         float* __restrict__ out, int p) {
    __shared__ float hs[4][64];
    const int f  = threadIdx.x & 63;
    const int tr = threadIdx.x >> 6;   // 0..3
    const int b  = blockIdx.x * 4 + tr;
    float acc = 0.f;
    for (int k0 = 0; k0 < HD; k0 += 64) {
        __syncthreads();
        {
            const int r = threadIdx.x >> 6, k = threadIdx.x & 63;
            const float v = h1[(size_t)(blockIdx.x * 4 + r) * HD + k0 + k];
            hs[r][k] = v > 0.f ? v : 0.f;
        }
        __syncthreads();
#pragma unroll 8
        for (int kk = 0; kk < 64; ++kk)
            acc += hs[tr][kk] * Wo[(size_t)(k0 + kk) * F + f];
    }
    out[((size_t)b * PRED + p) * F + f] = acc + bo[f];
}

// ---------------------------------------------------------------------------
extern "C" void kernel_launch(void* const* d_in, const int* in_sizes, int n_in,
                              void* d_out, int out_size, void* d_ws, size_t ws_size,
                              hipStream_t stream) {
    const float* x   = (const float*)d_in[0];
    const float* Wh  = (const float*)d_in[1];
    const float* bh  = (const float*)d_in[2];
    const float* Wih = (const float*)d_in[3];
    const float* Whh = (const float*)d_in[4];
    const float* bih = (const float*)d_in[5];
    const float* bhh = (const float*)d_in[6];
    const float* Wo  = (const float*)d_in[7];
    const float* bo  = (const float*)d_in[8];
    float* out = (float*)d_out;

    float* ws    = (float*)d_ws;
    float* Wfold = ws;                    // 64*1024
    float* bf0   = ws + 65536;            // 1024
    float* bf1   = ws + 66560;            // 1024
    float* h0b[2] = { ws + 67584,  ws + 67584 + 262144 };
    float* h1b[2] = { ws + 591872, ws + 591872 + 262144 };

    // zero initial hidden states (harness poisons ws; must init every call)
    hipMemsetAsync(h0b[0], 0, 262144 * sizeof(float), stream);
    hipMemsetAsync(h1b[0], 0, 262144 * sizeof(float), stream);

    fold_kernel<<<64, 256, 0, stream>>>(Wh, Wih, Wfold);
    bias_kernel<<<4, 256, 0, stream>>>(bh, Wih, bih, bhh, bf0, bf1);

    const float* Wih1 = Wih + (size_t)HD * HD;
    const float* Whh1 = Whh + (size_t)HD * HD;

    int cur = 0;
    for (int t = 0; t < S - 1; ++t) {            // t = 0..190
        layer0_step<<<512, 256, 0, stream>>>(x, t, Wfold, bf0, Whh,
                                             h0b[cur], h0b[cur ^ 1]);
        layer1_step<<<512, 256, 0, stream>>>(Wih1, Whh1, bf1,
                                             h0b[cur ^ 1], h1b[cur], h1b[cur ^ 1]);
        if (t >= S - 1 - PRED) {                 // t >= 143
            out_step<<<64, 256, 0, stream>>>(h1b[cur ^ 1], Wo, bo, out,
                                             t - (S - 1 - PRED));
        }
        cur ^= 1;
    }
}

// Round 2
// 5380.074 us; speedup vs baseline: 12.1988x; 12.1988x over previous
//
#include <hip/hip_runtime.h>
#include <hip/hip_bf16.h>

#define B    256
#define S    192
#define F    64
#define HD   1024
#define PRED 48
#define TSTART (S - 1 - PRED)   // 143

typedef __attribute__((ext_vector_type(8))) short short8;
typedef __attribute__((ext_vector_type(4))) float f32x4;

static __device__ __forceinline__ short f2bf(float f) {
    __hip_bfloat16 h = __float2bfloat16(f);
    return *reinterpret_cast<short*>(&h);
}

// ---------------------------------------------------------------------------
// fold_kernel: Wfold[f][n] = sum_hd W_hidden[f][hd] * Wih0[hd][n]   (fp32)
// ---------------------------------------------------------------------------
__global__ void fold_kernel(const float* __restrict__ Wh,
                            const float* __restrict__ Wih0,
                            float* __restrict__ Wfold) {
    const int n  = (blockIdx.x & 3) * 256 + threadIdx.x;
    const int f0 = (blockIdx.x >> 2) * 4;
    float a0 = 0.f, a1 = 0.f, a2 = 0.f, a3 = 0.f;
#pragma unroll 8
    for (int k = 0; k < HD; ++k) {
        const float w = Wih0[(size_t)k * HD + n];
        a0 += Wh[(f0 + 0) * HD + k] * w;
        a1 += Wh[(f0 + 1) * HD + k] * w;
        a2 += Wh[(f0 + 2) * HD + k] * w;
        a3 += Wh[(f0 + 3) * HD + k] * w;
    }
    Wfold[(f0 + 0) * HD + n] = a0;
    Wfold[(f0 + 1) * HD + n] = a1;
    Wfold[(f0 + 2) * HD + n] = a2;
    Wfold[(f0 + 3) * HD + n] = a3;
}

// ---------------------------------------------------------------------------
// bias_kernel: bf0[n] = b_hidden@Wih0[:,n] + bih0[n] + bhh0[n]; bf1 = bih1+bhh1
// ---------------------------------------------------------------------------
__global__ void bias_kernel(const float* __restrict__ bh,
                            const float* __restrict__ Wih0,
                            const float* __restrict__ bih,
                            const float* __restrict__ bhh,
                            float* __restrict__ bf0,
                            float* __restrict__ bf1) {
    const int n = blockIdx.x * 256 + threadIdx.x;
    float a = 0.f;
#pragma unroll 8
    for (int k = 0; k < HD; ++k) a += bh[k] * Wih0[(size_t)k * HD + n];
    bf0[n] = a + bih[n] + bhh[n];
    bf1[n] = bih[HD + n] + bhh[HD + n];
}

// ---------------------------------------------------------------------------
// transpose_cast: src fp32 [K][N] -> dst bf16 [N][K].  64x64 LDS tiles.
// grid = (K/64)*(N/64), block 256.
// ---------------------------------------------------------------------------
__global__ void transpose_cast(const float* __restrict__ src,
                               short* __restrict__ dst, int K, int N) {
    __shared__ float tile[64][65];
    const int nk = K >> 6;
    const int bk = blockIdx.x % nk;
    const int bn = blockIdx.x / nk;
    const int i  = threadIdx.x;
    // load 64x64 fp32 tile, coalesced (float4 per thread, 4 iters)
    {
        const int c4 = (i & 15) * 4;
        for (int it = 0; it < 4; ++it) {
            const int k = (i >> 4) + it * 16;
            const float4 v = *reinterpret_cast<const float4*>(
                &src[(size_t)(bk * 64 + k) * N + bn * 64 + c4]);
            tile[k][c4 + 0] = v.x; tile[k][c4 + 1] = v.y;
            tile[k][c4 + 2] = v.z; tile[k][c4 + 3] = v.w;
        }
    }
    __syncthreads();
    // write: thread i owns dst row n = i>>2, 16 k's starting (i&3)*16
    {
        const int n  = i >> 2;
        const int kb = (i & 3) * 16;
        short* dp = &dst[(size_t)(bn * 64 + n) * K + bk * 64 + kb];
#pragma unroll
        for (int j = 0; j < 16; ++j) dp[j] = f2bf(tile[kb + j][n]);
    }
}

// ---------------------------------------------------------------------------
// stepA: h0_new = tanh( x[:,t,:]@Wfold + bf0 + h0_prev@Whh0 )
// grid 256 = (rowtile 0..15)<<4 | coltile; block 256 = 4 waves; wave: 16x16
// tile over full K via direct-global MFMA loads. No LDS, no barriers.
// ---------------------------------------------------------------------------
__global__ __launch_bounds__(256) void stepA(
    const float* __restrict__ x, int t,
    const short* __restrict__ WfoldT, const float* __restrict__ bf0,
    const short* __restrict__ WhhT0,
    const short* __restrict__ h0p, short* __restrict__ h0n) {
    const int rt = blockIdx.x >> 4, ct = blockIdx.x & 15;
    const int w = threadIdx.x >> 6, l = threadIdx.x & 63;
    const int lr = l & 15, kg = l >> 4;
    const int m0 = rt * 16, n0 = ct * 64 + w * 16;
    const int arow = m0 + lr, bcol = n0 + lr;

    f32x4 acc = {0.f, 0.f, 0.f, 0.f};

    // x-path: K=64, A = bf16(x[arow][t][.]), B = WfoldT
    {
        const f32x4* xp = reinterpret_cast<const f32x4*>(
            &x[((size_t)arow * S + t) * F + kg * 8]);
        const f32x4 u0 = xp[0], u1 = xp[1];      // k = kg*8 .. kg*8+7
        const f32x4 v0 = xp[8], v1 = xp[9];      // k = 32+kg*8 ..
        short8 a0, a1;
#pragma unroll
        for (int j = 0; j < 4; ++j) {
            a0[j]     = f2bf(u0[j]); a0[j + 4] = f2bf(u1[j]);
            a1[j]     = f2bf(v0[j]); a1[j + 4] = f2bf(v1[j]);
        }
        const short* bp = WfoldT + bcol * 64 + kg * 8;
        const short8 b0 = *reinterpret_cast<const short8*>(bp);
        const short8 b1 = *reinterpret_cast<const short8*>(bp + 32);
        acc = __builtin_amdgcn_mfma_f32_16x16x32_bf16(a0, b0, acc, 0, 0, 0);
        acc = __builtin_amdgcn_mfma_f32_16x16x32_bf16(a1, b1, acc, 0, 0, 0);
    }
    if (t > 0) {
        const short* ap = h0p + arow * HD + kg * 8;
        const short* bp = WhhT0 + bcol * HD + kg * 8;
#pragma unroll 8
        for (int k0 = 0; k0 < HD; k0 += 32) {
            const short8 a = *reinterpret_cast<const short8*>(ap + k0);
            const short8 b = *reinterpret_cast<const short8*>(bp + k0);
            acc = __builtin_amdgcn_mfma_f32_16x16x32_bf16(a, b, acc, 0, 0, 0);
        }
    }
    const float bb = bf0[bcol];
    const int rb = m0 + kg * 4;
#pragma unroll
    for (int r = 0; r < 4; ++r) {
        const float v = tanhf(acc[r] + bb);
        h0n[(rb + r) * HD + bcol] = f2bf(v);
    }
}

// ---------------------------------------------------------------------------
// stepC: h1_new = tanh( h0_new@Wih1 + h1_prev@Whh1 + bf1 )
//        + (t>=143) Hbuf[b][t-143][n] = bf16(relu(h1_new))
// ---------------------------------------------------------------------------
__global__ __launch_bounds__(256) void stepC(
    int t, const short* __restrict__ WihT1, const short* __restrict__ WhhT1,
    const float* __restrict__ bf1,
    const short* __restrict__ h0n, const short* __restrict__ h1p,
    short* __restrict__ h1n, short* __restrict__ Hbuf) {
    const int rt = blockIdx.x >> 4, ct = blockIdx.x & 15;
    const int w = threadIdx.x >> 6, l = threadIdx.x & 63;
    const int lr = l & 15, kg = l >> 4;
    const int m0 = rt * 16, n0 = ct * 64 + w * 16;
    const int arow = m0 + lr, bcol = n0 + lr;

    f32x4 acc = {0.f, 0.f, 0.f, 0.f};
    {
        const short* ap = h0n + arow * HD + kg * 8;
        const short* bp = WihT1 + bcol * HD + kg * 8;
#pragma unroll 8
        for (int k0 = 0; k0 < HD; k0 += 32) {
            const short8 a = *reinterpret_cast<const short8*>(ap + k0);
            const short8 b = *reinterpret_cast<const short8*>(bp + k0);
            acc = __builtin_amdgcn_mfma_f32_16x16x32_bf16(a, b, acc, 0, 0, 0);
        }
    }
    if (t > 0) {
        const short* ap = h1p + arow * HD + kg * 8;
        const short* bp = WhhT1 + bcol * HD + kg * 8;
#pragma unroll 8
        for (int k0 = 0; k0 < HD; k0 += 32) {
            const short8 a = *reinterpret_cast<const short8*>(ap + k0);
            const short8 b = *reinterpret_cast<const short8*>(bp + k0);
            acc = __builtin_amdgcn_mfma_f32_16x16x32_bf16(a, b, acc, 0, 0, 0);
        }
    }
    const float bb = bf1[bcol];
    const int rb = m0 + kg * 4;
#pragma unroll
    for (int r = 0; r < 4; ++r) {
        const float v = tanhf(acc[r] + bb);
        h1n[(rb + r) * HD + bcol] = f2bf(v);
        if (t >= TSTART) {
            const float rv = v > 0.f ? v : 0.f;
            Hbuf[((size_t)(rb + r) * PRED + (t - TSTART)) * HD + bcol] = f2bf(rv);
        }
    }
}

// ---------------------------------------------------------------------------
// outgemm: out[r][f] = Hbuf_row[r] @ WoT[f] + bo[f];  M=12288, N=64, K=1024
// grid 192 blocks, 4 waves; wave: 16 rows x 64 cols (4 acc frags).
// ---------------------------------------------------------------------------
__global__ __launch_bounds__(256) void outgemm(
    const short* __restrict__ Hbuf, const short* __restrict__ WoT,
    const float* __restrict__ bo, float* __restrict__ out) {
    const int w = threadIdx.x >> 6, l = threadIdx.x & 63;
    const int lr = l & 15, kg = l >> 4;
    const int m0 = blockIdx.x * 64 + w * 16;
    const int arow = m0 + lr;

    f32x4 acc[4] = {{0.f,0.f,0.f,0.f},{0.f,0.f,0.f,0.f},
                    {0.f,0.f,0.f,0.f},{0.f,0.f,0.f,0.f}};
    const short* ap = Hbuf + (size_t)arow * HD + kg * 8;
    const short* bp = WoT + lr * HD + kg * 8;
#pragma unroll 4
    for (int k0 = 0; k0 < HD; k0 += 32) {
        const short8 a = *reinterpret_cast<const short8*>(ap + k0);
#pragma unroll
        for (int c = 0; c < 4; ++c) {
            const short8 b = *reinterpret_cast<const short8*>(bp + c * 16 * HD + k0);
            acc[c] = __builtin_amdgcn_mfma_f32_16x16x32_bf16(a, b, acc[c], 0, 0, 0);
        }
    }
    const int rb = m0 + kg * 4;
#pragma unroll
    for (int c = 0; c < 4; ++c) {
        const float bb = bo[c * 16 + lr];
#pragma unroll
        for (int r = 0; r < 4; ++r)
            out[(size_t)(rb + r) * F + c * 16 + lr] = acc[c][r] + bb;
    }
}

// ---------------------------------------------------------------------------
extern "C" void kernel_launch(void* const* d_in, const int* in_sizes, int n_in,
                              void* d_out, int out_size, void* d_ws, size_t ws_size,
                              hipStream_t stream) {
    const float* x   = (const float*)d_in[0];
    const float* Wh  = (const float*)d_in[1];
    const float* bh  = (const float*)d_in[2];
    const float* Wih = (const float*)d_in[3];
    const float* Whh = (const float*)d_in[4];
    const float* bih = (const float*)d_in[5];
    const float* bhh = (const float*)d_in[6];
    const float* Wo  = (const float*)d_in[7];
    const float* bo  = (const float*)d_in[8];
    float* out = (float*)d_out;

    char* p = (char*)d_ws;
    float* Wfold  = (float*)p; p += (size_t)F * HD * 4;          // 256 KB
    float* bf0    = (float*)p; p += HD * 4;
    float* bf1    = (float*)p; p += HD * 4;
    short* WfoldT = (short*)p; p += (size_t)HD * F * 2;          // 128 KB
    short* WhhT0  = (short*)p; p += (size_t)HD * HD * 2;         // 2 MB
    short* WihT1  = (short*)p; p += (size_t)HD * HD * 2;
    short* WhhT1  = (short*)p; p += (size_t)HD * HD * 2;
    short* WoT    = (short*)p; p += (size_t)F * HD * 2;          // 128 KB
    short* h0b[2] = {(short*)p, (short*)(p + (size_t)B * HD * 2)};
    p += (size_t)2 * B * HD * 2;                                 // 1 MB
    short* h1b[2] = {(short*)p, (short*)(p + (size_t)B * HD * 2)};
    p += (size_t)2 * B * HD * 2;                                 // 1 MB
    short* Hbuf   = (short*)p;                                   // 24 MB

    // ---- prep (runs every call; trivial vs total) ----
    fold_kernel<<<64, 256, 0, stream>>>(Wh, Wih, Wfold);
    bias_kernel<<<4, 256, 0, stream>>>(bh, Wih, bih, bhh, bf0, bf1);
    transpose_cast<<<16, 256, 0, stream>>>(Wfold, WfoldT, F, HD);        // [64][1024]->[1024][64]
    transpose_cast<<<256, 256, 0, stream>>>(Whh, WhhT0, HD, HD);
    transpose_cast<<<256, 256, 0, stream>>>(Wih + (size_t)HD * HD, WihT1, HD, HD);
    transpose_cast<<<256, 256, 0, stream>>>(Whh + (size_t)HD * HD, WhhT1, HD, HD);
    transpose_cast<<<16, 256, 0, stream>>>(Wo, WoT, HD, F);              // [1024][64]->[64][1024]

    // ---- sequential recurrence ----
    int cur = 0;
    for (int t = 0; t < S - 1; ++t) {
        stepA<<<256, 256, 0, stream>>>(x, t, WfoldT, bf0, WhhT0,
                                       h0b[cur], h0b[cur ^ 1]);
        stepC<<<256, 256, 0, stream>>>(t, WihT1, WhhT1, bf1,
                                       h0b[cur ^ 1], h1b[cur], h1b[cur ^ 1], Hbuf);
        cur ^= 1;
    }
    // ---- batched output projection ----
    outgemm<<<192, 256, 0, stream>>>(Hbuf, WoT, bo, out);
}